// Round 8
// baseline (732.606 us; speedup 1.0000x reference)
//
#include <hip/hip_runtime.h>
#include <hip/hip_bf16.h>

#define NN   20000
#define NE   320000
#define HID  256
#define EDIM 128
#define DDIM 64
#define TDIM 256
#define INCH 704

typedef __attribute__((ext_vector_type(8))) short bf16x8;
typedef __attribute__((ext_vector_type(4))) float f32x4;
typedef __attribute__((ext_vector_type(4))) unsigned int u32x4;

__device__ __forceinline__ unsigned short f2bu(float x) {
    return __bfloat16_as_ushort(__float2bfloat16(x));
}
__device__ __forceinline__ unsigned pk2(float lo, float hi) {
    return (unsigned)f2bu(lo) | ((unsigned)f2bu(hi) << 16);
}
__device__ __forceinline__ float silu_f(float x) {
    return x / (1.0f + __expf(-x));
}

// Pack fp32 [K][Nc] row-major weight into bf16 MFMA B-fragment order:
// frag element j of lane l of tile (kt,nt) = B[kt*32 + (l>>4)*8 + j][nt*16 + (l&15)]
// stored at dst[((kt*NT+nt)*64 + l)*8 + j]. A staging uses the same (l>>4, j)->k
// mapping, so any HW within-K-tile permutation cancels.
__global__ void pack_weights(const float* __restrict__ src, unsigned short* __restrict__ dst,
                             int K, int Nc) {
    int KT = K >> 5, NT = Nc >> 4;
    int total = KT * NT * 64;
    int idx = blockIdx.x * blockDim.x + threadIdx.x;
    if (idx >= total) return;
    int lane = idx & 63;
    int tile = idx >> 6;
    int nt = tile % NT, kt = tile / NT;
    int n = nt * 16 + (lane & 15);
    int k0 = kt * 32 + (lane >> 4) * 8;
    alignas(16) unsigned short v[8];
#pragma unroll
    for (int j = 0; j < 8; ++j) v[j] = f2bu(src[(size_t)(k0 + j) * Nc + n]);
    *reinterpret_cast<u32x4*>(dst + (size_t)idx * 8) = *reinterpret_cast<const u32x4*>(v);
}

__global__ void init_out(const float* __restrict__ pos, float* __restrict__ out, int n) {
    int i = blockIdx.x * blockDim.x + threadIdx.x;
    if (i < n) out[i] = pos[i];
}

__global__ __launch_bounds__(512, 4) void edge_kernel(
    const float* __restrict__ h, const float* __restrict__ pos,
    const float* __restrict__ edge_attr, const float* __restrict__ dist,
    const float* __restrict__ time_emb, const int* __restrict__ edge_index,
    const float* __restrict__ b_time, const float* __restrict__ b_in,
    const float* __restrict__ b_c1, const float* __restrict__ W_c2,
    const float* __restrict__ coord_scale,
    const unsigned short* __restrict__ pWtime, const unsigned short* __restrict__ pWin,
    const unsigned short* __restrict__ pWc1,
    float* __restrict__ out)
{
    // 8 waves per block, 64 edges per block; each wave owns a 64x32 output slice.
    // launch_bounds(512,4): 128 unified regs/wave -> 2 blocks/CU (16 waves).
    // Register budget is the binding constraint: accY=32 acc, prefetch = 2x8
    // parity-static buffers (rA even-issue, rB odd-issue), no rotation copies.
    __shared__ __align__(16) unsigned char smemT[64 * 264 * 2];
    __shared__ __align__(16) unsigned char smem2[64 * 264 * 2];
    __hip_bfloat16 (*sT)[264]    = reinterpret_cast<__hip_bfloat16(*)[264]>(smemT);
    __hip_bfloat16 (*sU)[264]    = reinterpret_cast<__hip_bfloat16(*)[264]>(smem2);
    __hip_bfloat16 (*sX)[64][72] = reinterpret_cast<__hip_bfloat16(*)[64][72]>(smem2);
    __shared__ float sSum[64], sSq[64], sS[64];
    __shared__ int sRow[64], sCol[64];

    const int tid = threadIdx.x;
    const int wave = tid >> 6, lane = tid & 63;
    const int lq = lane >> 4, lr = lane & 15;
    const int e0 = blockIdx.x * 64;
    const int el = tid >> 3, part = tid & 7;   // staging: 64 edges x 8 parts (8 floats each)

    const int rIdx = edge_index[e0 + el];
    const int cIdx = edge_index[NE + e0 + el];

    // chunk kn covers X cols [kn*64, kn*64+64)
    auto chunk_ptr = [&](int kn) -> const float* {
        const float* p;
        if (kn < 4)       p = h + (size_t)rIdx * HID + kn * 64;
        else if (kn < 8)  p = h + (size_t)cIdx * HID + (kn - 4) * 64;
        else if (kn < 10) p = edge_attr + (size_t)(e0 + el) * EDIM + (kn - 8) * 64;
        else              p = dist + (size_t)(e0 + el) * DDIM;
        return p + part * 8;
    };

    // prologue: c0 -> rA, c1 -> rB; latency hides under sT staging below
    float rA[8], rB[8];
    {
        const float* p = chunk_ptr(0);
        *reinterpret_cast<float4*>(&rA[0]) = *reinterpret_cast<const float4*>(p);
        *reinterpret_cast<float4*>(&rA[4]) = *reinterpret_cast<const float4*>(p + 4);
        const float* q = chunk_ptr(1);
        *reinterpret_cast<float4*>(&rB[0]) = *reinterpret_cast<const float4*>(q);
        *reinterpret_cast<float4*>(&rB[4]) = *reinterpret_cast<const float4*>(q + 4);
    }

    if (tid < 64) {
        sRow[tid] = edge_index[e0 + tid];
        sCol[tid] = edge_index[NE + e0 + tid];
        sSum[tid] = 0.f; sSq[tid] = 0.f; sS[tid] = 0.f;
    }

    // ---- stage silu(time_emb) into sT (bf16), once: 32 floats/thread ----
    {
        const float* p = time_emb + (size_t)(e0 + el) * TDIM + part * 32;
#pragma unroll
        for (int j = 0; j < 4; ++j) {
            float4 a = *reinterpret_cast<const float4*>(p + j * 8);
            float4 b = *reinterpret_cast<const float4*>(p + j * 8 + 4);
            u32x4 w;
            w.x = pk2(silu_f(a.x), silu_f(a.y)); w.y = pk2(silu_f(a.z), silu_f(a.w));
            w.z = pk2(silu_f(b.x), silu_f(b.y)); w.w = pk2(silu_f(b.z), silu_f(b.w));
            *reinterpret_cast<u32x4*>(&sT[el][part * 32 + j * 8]) = w;
        }
    }

    // write c0 (rA) into sX[0]; rA free after this
    {
        u32x4 w;
        w.x = pk2(rA[0], rA[1]); w.y = pk2(rA[2], rA[3]);
        w.z = pk2(rA[4], rA[5]); w.w = pk2(rA[6], rA[7]);
        *reinterpret_cast<u32x4*>(&sX[0][el][part * 8]) = w;
    }
    __syncthreads();   // B1

    // ---- Phase Y: BK=64, depth-2 prefetch with parity-static buffers ----
    // even kt: issue c(kt+2)->rA, MFMA sX[kt&1], write rB->sX[(kt&1)^1]
    // odd  kt: issue c(kt+2)->rB, MFMA sX[kt&1], write rA->sX[(kt&1)^1]
    f32x4 accY[4][2];
#pragma unroll
    for (int m = 0; m < 4; ++m)
#pragma unroll
        for (int n = 0; n < 2; ++n) accY[m][n] = (f32x4){0.f, 0.f, 0.f, 0.f};

#define Y_ITER(KT, RISSUE, RWRITE)                                                        \
    {                                                                                     \
        const int buf_ = (KT) & 1;                                                        \
        if ((KT) < 9) {                                                                   \
            const float* p_ = chunk_ptr((KT) + 2);                                        \
            *reinterpret_cast<float4*>(&RISSUE[0]) = *reinterpret_cast<const float4*>(p_);\
            *reinterpret_cast<float4*>(&RISSUE[4]) = *reinterpret_cast<const float4*>(p_ + 4);\
        }                                                                                 \
        _Pragma("unroll")                                                                 \
        for (int kq = 0; kq < 2; ++kq) {                                                  \
            bf16x8 afr[4];                                                                \
            _Pragma("unroll")                                                             \
            for (int m = 0; m < 4; ++m)                                                   \
                afr[m] = *reinterpret_cast<const bf16x8*>(&sX[buf_][m * 16 + lr][kq * 32 + lq * 8]); \
            _Pragma("unroll")                                                             \
            for (int n = 0; n < 2; ++n) {                                                 \
                bf16x8 bfr = *reinterpret_cast<const bf16x8*>(                            \
                    pWin + ((size_t)((2 * (KT) + kq) * 16 + 2 * wave + n) * 64 + lane) * 8); \
                _Pragma("unroll")                                                         \
                for (int m = 0; m < 4; ++m)                                               \
                    accY[m][n] = __builtin_amdgcn_mfma_f32_16x16x32_bf16(afr[m], bfr, accY[m][n], 0, 0, 0); \
            }                                                                             \
        }                                                                                 \
        if ((KT) < 10) {                                                                  \
            u32x4 w_;                                                                     \
            w_.x = pk2(RWRITE[0], RWRITE[1]); w_.y = pk2(RWRITE[2], RWRITE[3]);           \
            w_.z = pk2(RWRITE[4], RWRITE[5]); w_.w = pk2(RWRITE[6], RWRITE[7]);           \
            *reinterpret_cast<u32x4*>(&sX[buf_ ^ 1][el][part * 8]) = w_;                  \
        }                                                                                 \
        __syncthreads();                                                                  \
    }

#pragma unroll 1
    for (int k2 = 0; k2 < 6; ++k2) {
        const int kt = 2 * k2;
        Y_ITER(kt, rA, rB);
        if (kt + 1 < 11) Y_ITER(kt + 1, rB, rA);
    }
#undef Y_ITER
    // sX region dead after final barrier

    // + b_in
#pragma unroll
    for (int n = 0; n < 2; ++n) {
        float bi = b_in[(2 * wave + n) * 16 + lr];
#pragma unroll
        for (int m = 0; m < 4; ++m) {
            accY[m][n].x += bi; accY[m][n].y += bi; accY[m][n].z += bi; accY[m][n].w += bi;
        }
    }

    // LayerNorm stats across 256 cols (8 waves x 32 cols each)
#pragma unroll
    for (int m = 0; m < 4; ++m) {
#pragma unroll
        for (int r = 0; r < 4; ++r) {
            float v0 = accY[m][0][r], v1 = accY[m][1][r];
            float s1 = v0 + v1;
            float s2 = v0 * v0 + v1 * v1;
#pragma unroll
            for (int off = 1; off < 16; off <<= 1) {
                s1 += __shfl_xor(s1, off, 64);
                s2 += __shfl_xor(s2, off, 64);
            }
            if (lr == 0) {
                atomicAdd(&sSum[m * 16 + lq * 4 + r], s1);
                atomicAdd(&sSq[m * 16 + lq * 4 + r], s2);
            }
        }
    }
    __syncthreads();

    // normalize in place: accY <- LN(Y)
#pragma unroll
    for (int m = 0; m < 4; ++m) {
#pragma unroll
        for (int r = 0; r < 4; ++r) {
            int e = m * 16 + lq * 4 + r;
            float mu = sSum[e] * (1.0f / 256.0f);
            float var = sSq[e] * (1.0f / 256.0f) - mu * mu;
            float rs = rsqrtf(var + 1e-6f);
#pragma unroll
            for (int n = 0; n < 2; ++n)
                accY[m][n][r] = (accY[m][n][r] - mu) * rs;
        }
    }

    // ---- Phase T: FiLM via two passes (scale, shift), m-split halves (acc2 = 16 regs) ----
#pragma unroll
    for (int pass = 0; pass < 2; ++pass) {
#pragma unroll
        for (int mh = 0; mh < 2; ++mh) {
            f32x4 acc2[2][2];
#pragma unroll
            for (int mm = 0; mm < 2; ++mm)
#pragma unroll
                for (int n = 0; n < 2; ++n) acc2[mm][n] = (f32x4){0.f, 0.f, 0.f, 0.f};
#pragma unroll
            for (int kt = 0; kt < 8; ++kt) {
                bf16x8 afr[2];
#pragma unroll
                for (int mm = 0; mm < 2; ++mm)
                    afr[mm] = *reinterpret_cast<const bf16x8*>(
                        &sT[(2 * mh + mm) * 16 + lr][kt * 32 + lq * 8]);
#pragma unroll
                for (int n = 0; n < 2; ++n) {
                    int ncol = (pass == 0) ? (16 + 2 * wave + n) : (2 * wave + n);
                    bf16x8 bfr = *reinterpret_cast<const bf16x8*>(
                        pWtime + ((size_t)(kt * 32 + ncol) * 64 + lane) * 8);
#pragma unroll
                    for (int mm = 0; mm < 2; ++mm)
                        acc2[mm][n] = __builtin_amdgcn_mfma_f32_16x16x32_bf16(afr[mm], bfr, acc2[mm][n], 0, 0, 0);
                }
            }
#pragma unroll
            for (int n = 0; n < 2; ++n) {
                float bt = (pass == 0) ? b_time[256 + (2 * wave + n) * 16 + lr]
                                       : b_time[(2 * wave + n) * 16 + lr];
#pragma unroll
                for (int mm = 0; mm < 2; ++mm) {
                    int m = 2 * mh + mm;
#pragma unroll
                    for (int r = 0; r < 4; ++r) {
                        if (pass == 0) accY[m][n][r] *= (1.0f + bt + acc2[mm][n][r]);
                        else           accY[m][n][r] += bt + acc2[mm][n][r];
                    }
                }
            }
        }
    }

    // write U (bf16) into sU (sX region dead)
#pragma unroll
    for (int m = 0; m < 4; ++m) {
#pragma unroll
        for (int r = 0; r < 4; ++r) {
            int e = m * 16 + lq * 4 + r;
#pragma unroll
            for (int n = 0; n < 2; ++n)
                sU[e][(2 * wave + n) * 16 + lr] = __float2bfloat16(accY[m][n][r]);
        }
    }
    __syncthreads();

    // ---- Phase Z: Z = U @ W_c1 (barrier-free inner loop) ----
    f32x4 accZ[4][2];
#pragma unroll
    for (int m = 0; m < 4; ++m)
#pragma unroll
        for (int n = 0; n < 2; ++n) accZ[m][n] = (f32x4){0.f, 0.f, 0.f, 0.f};

#pragma unroll
    for (int kt = 0; kt < 8; ++kt) {
        bf16x8 afr[4];
#pragma unroll
        for (int m = 0; m < 4; ++m)
            afr[m] = *reinterpret_cast<const bf16x8*>(&sU[m * 16 + lr][kt * 32 + lq * 8]);
#pragma unroll
        for (int n = 0; n < 2; ++n) {
            bf16x8 bfr = *reinterpret_cast<const bf16x8*>(
                pWc1 + ((size_t)(kt * 16 + 2 * wave + n) * 64 + lane) * 8);
#pragma unroll
            for (int m = 0; m < 4; ++m)
                accZ[m][n] = __builtin_amdgcn_mfma_f32_16x16x32_bf16(afr[m], bfr, accZ[m][n], 0, 0, 0);
        }
    }

    // s = silu(Z + b_c1) @ W_c2 (per-edge scalar)
#pragma unroll
    for (int m = 0; m < 4; ++m) {
        float ps0 = 0.f, ps1 = 0.f, ps2 = 0.f, ps3 = 0.f;
#pragma unroll
        for (int n = 0; n < 2; ++n) {
            int colg = (2 * wave + n) * 16 + lr;
            float bc = b_c1[colg];
            float w2 = W_c2[colg];
            ps0 += silu_f(accZ[m][n][0] + bc) * w2;
            ps1 += silu_f(accZ[m][n][1] + bc) * w2;
            ps2 += silu_f(accZ[m][n][2] + bc) * w2;
            ps3 += silu_f(accZ[m][n][3] + bc) * w2;
        }
        float ps[4] = {ps0, ps1, ps2, ps3};
#pragma unroll
        for (int r = 0; r < 4; ++r) {
            float v = ps[r];
#pragma unroll
            for (int off = 1; off < 16; off <<= 1) v += __shfl_xor(v, off, 64);
            if (lr == 0) atomicAdd(&sS[m * 16 + lq * 4 + r], v);
        }
    }
    __syncthreads();

    // ---- epilogue: coord update + segment-sum atomics ----
    if (tid < 64) {
        int e = tid;
        float inv = tanhf(sS[e]);
        int rI = sRow[e], cI = sCol[e];
        float dx = pos[rI * 3 + 0] - pos[cI * 3 + 0];
        float dy = pos[rI * 3 + 1] - pos[cI * 3 + 1];
        float dz = pos[rI * 3 + 2] - pos[cI * 3 + 2];
        float nrm = sqrtf(dx * dx + dy * dy + dz * dz);
        float f = coord_scale[0] * inv / fmaxf(nrm, 1e-8f);
        atomicAdd(&out[rI * 3 + 0], dx * f);
        atomicAdd(&out[rI * 3 + 1], dy * f);
        atomicAdd(&out[rI * 3 + 2], dz * f);
    }
}

extern "C" void kernel_launch(void* const* d_in, const int* in_sizes, int n_in,
                              void* d_out, int out_size, void* d_ws, size_t ws_size,
                              hipStream_t stream) {
    const float* h          = (const float*)d_in[0];
    const float* pos        = (const float*)d_in[1];
    const float* edge_attr  = (const float*)d_in[2];
    const float* dist       = (const float*)d_in[3];
    const float* time_emb   = (const float*)d_in[4];
    const int*   edge_index = (const int*)d_in[5];
    const float* W_time     = (const float*)d_in[6];
    const float* b_time     = (const float*)d_in[7];
    const float* W_in       = (const float*)d_in[8];
    const float* b_in       = (const float*)d_in[9];
    const float* W_c1       = (const float*)d_in[10];
    const float* b_c1       = (const float*)d_in[11];
    const float* W_c2       = (const float*)d_in[12];
    const float* coord_scale= (const float*)d_in[13];
    float* out = (float*)d_out;

    unsigned short* pWin   = (unsigned short*)d_ws;                       // 704*256*2 = 360448 B
    unsigned short* pWtime = (unsigned short*)((char*)d_ws + 360448);     // 256*512*2 = 262144 B
    unsigned short* pWc1   = (unsigned short*)((char*)d_ws + 622592);     // 256*256*2 = 131072 B

    pack_weights<<<88, 256, 0, stream>>>(W_in,   pWin,   INCH, HID);
    pack_weights<<<64, 256, 0, stream>>>(W_time, pWtime, TDIM, 2 * HID);
    pack_weights<<<32, 256, 0, stream>>>(W_c1,   pWc1,   HID,  HID);
    init_out<<<(3 * NN + 255) / 256, 256, 0, stream>>>(pos, out, 3 * NN);

    edge_kernel<<<NE / 64, 512, 0, stream>>>(
        h, pos, edge_attr, dist, time_emb, edge_index,
        b_time, b_in, b_c1, W_c2, coord_scale,
        pWtime, pWin, pWc1, out);
}